// Round 2
// baseline (673.223 us; speedup 1.0000x reference)
//
#include <hip/hip_runtime.h>
#include <cmath>

// ---------------------------------------------------------------------------
// SelfAttention: B=8, S=2048, D=768, fp32 in/out.
//   Q = x Wq^T ; K = x Wk^T ; V = x Wv^T          (bf16 MFMA, fp32 accum)
//   Sc = Q K^T / sqrt(D)  -> softmax rows -> out1 (fp32, written to d_out)
//   wv = attn V                                    -> out0
//
// Scratch plan (R1 fix: previous 75.5 MB ws footprint overran ws_size and
// stomped adjacent allocations — post-timing divergence):
//   Qb bf16 [16384][768]  -> lives in d_out's out0 region [0 : 25.2 MB)
//   Kb bf16 [16384][768]  -> lives in d_out's out0 region [25.2 : 50.3 MB)
//     (out0 is 8*2048*768 fp32 = 50,331,648 B — exact fit; dead after the
//      scores GEMM, overwritten by the final PV kernel)
//   Vt bf16 [8][768][2048] -> d_ws (25.2 MB — the ONLY ws use)
// ---------------------------------------------------------------------------

typedef __bf16 v8bf __attribute__((ext_vector_type(8)));
typedef float  v4f  __attribute__((ext_vector_type(4)));
typedef unsigned short u16;

__device__ __forceinline__ u16 f2bf(float f) {
  union { float f; unsigned u; } v; v.f = f;
  unsigned r = v.u + 0x7fffu + ((v.u >> 16) & 1u);   // round-to-nearest-even
  return (u16)(r >> 16);
}

// stage 8 elements (along K) into LDS as bf16
__device__ __forceinline__ void stage8(const u16* src, u16* dst) {
  *(uint4*)dst = *(const uint4*)src;                  // already bf16
}
__device__ __forceinline__ void stage8(const float* src, u16* dst) {
  float4 f0 = *(const float4*)(src);
  float4 f1 = *(const float4*)(src + 4);
  union { uint4 u; u16 h[8]; } pk;
  pk.h[0] = f2bf(f0.x); pk.h[1] = f2bf(f0.y); pk.h[2] = f2bf(f0.z); pk.h[3] = f2bf(f0.w);
  pk.h[4] = f2bf(f1.x); pk.h[5] = f2bf(f1.y); pk.h[6] = f2bf(f1.z); pk.h[7] = f2bf(f1.w);
  *(uint4*)dst = pk.u;
}

enum { OUT_F32 = 0, OUT_BF16 = 1, OUT_VT_BF16 = 2 };

constexpr int BM = 64, BN = 64, BK = 32, PAD = 8;

// C[M,N] = alpha * A[M,K] * B[N,K]^T   (NT GEMM, K contiguous in both)
// grid.x = M/64, grid.y = N/64, grid.z = batch; 256 threads.
template <typename TA, typename TB, int MODE>
__global__ __launch_bounds__(256)
void gemm_nt(const TA* __restrict__ Ag, const TB* __restrict__ Bg,
             void* __restrict__ Cg, int K, int lda, int ldb, int ldc,
             long long sA, long long sB, long long sC, float alpha) {
  __shared__ alignas(16) u16 As[BM][BK + PAD];   // row stride 80 B (16B aligned)
  __shared__ alignas(16) u16 Bs[BN][BK + PAD];

  const int z = blockIdx.z;
  const TA* A = Ag + (size_t)z * (size_t)sA;
  const TB* B = Bg + (size_t)z * (size_t)sB;

  const int m0 = blockIdx.x * BM;
  const int n0 = blockIdx.y * BN;

  const int t    = threadIdx.x;
  const int srow = t >> 2;            // 0..63 staging row
  const int skb  = (t & 3) * 8;       // 0/8/16/24 staging k-offset

  const int lane = t & 63;
  const int wid  = t >> 6;
  const int mh   = (wid & 1) * 32;    // wave's 32x32 quadrant
  const int nh   = (wid >> 1) * 32;
  const int fr   = lane & 15;         // fragment row (m or n)
  const int fk   = (lane >> 4) * 8;   // fragment k offset (quad*8)

  v4f a00 = {0.f,0.f,0.f,0.f}, a01 = {0.f,0.f,0.f,0.f};
  v4f a10 = {0.f,0.f,0.f,0.f}, a11 = {0.f,0.f,0.f,0.f};

  const int nk = K / BK;
  for (int kt = 0; kt < nk; ++kt) {
    const int k0 = kt * BK;
    stage8(A + (size_t)(m0 + srow) * lda + k0 + skb, &As[srow][skb]);
    stage8(B + (size_t)(n0 + srow) * ldb + k0 + skb, &Bs[srow][skb]);
    __syncthreads();

    v8bf af0 = *(const v8bf*)&As[mh + fr][fk];
    v8bf af1 = *(const v8bf*)&As[mh + 16 + fr][fk];
    v8bf bf0 = *(const v8bf*)&Bs[nh + fr][fk];
    v8bf bf1 = *(const v8bf*)&Bs[nh + 16 + fr][fk];
    a00 = __builtin_amdgcn_mfma_f32_16x16x32_bf16(af0, bf0, a00, 0, 0, 0);
    a01 = __builtin_amdgcn_mfma_f32_16x16x32_bf16(af0, bf1, a01, 0, 0, 0);
    a10 = __builtin_amdgcn_mfma_f32_16x16x32_bf16(af1, bf0, a10, 0, 0, 0);
    a11 = __builtin_amdgcn_mfma_f32_16x16x32_bf16(af1, bf1, a11, 0, 0, 0);
    __syncthreads();
  }

  // C/D layout: col = lane&15, row = (lane>>4)*4 + reg
  auto epi = [&](v4f v, int mi, int ni) {
    const int grow0 = m0 + mh + mi * 16 + (lane >> 4) * 4;
    const int gcol  = n0 + nh + ni * 16 + fr;
    if constexpr (MODE == OUT_F32) {
      float* C = (float*)Cg + (size_t)z * (size_t)sC;
#pragma unroll
      for (int r = 0; r < 4; ++r)
        C[(size_t)(grow0 + r) * ldc + gcol] = v[r] * alpha;
    } else if constexpr (MODE == OUT_BF16) {
      u16* C = (u16*)Cg;
#pragma unroll
      for (int r = 0; r < 4; ++r)
        C[(size_t)(grow0 + r) * ldc + gcol] = f2bf(v[r] * alpha);
    } else {  // OUT_VT_BF16: C[b][col][s], b = grow>>11, s = grow&2047
      u16* C = (u16*)Cg;
      size_t base = (size_t)(grow0 >> 11) * (768ull * 2048ull) +
                    (size_t)gcol * 2048ull + (size_t)(grow0 & 2047);
      ushort4 st;
      st.x = f2bf(v[0]); st.y = f2bf(v[1]); st.z = f2bf(v[2]); st.w = f2bf(v[3]);
      *(ushort4*)&C[base] = st;   // 4 consecutive s -> 8B store
    }
  };
  epi(a00, 0, 0); epi(a01, 0, 1); epi(a10, 1, 0); epi(a11, 1, 1);
}

// in-place softmax over rows of 2048 fp32; one block per row
__global__ __launch_bounds__(256) void softmax_rows(float* __restrict__ w) {
  float* p = w + (size_t)blockIdx.x * 2048;
  const int t = threadIdx.x;
  float4 a = *(float4*)(p + t * 4);
  float4 b = *(float4*)(p + 1024 + t * 4);

  float mx = fmaxf(fmaxf(fmaxf(a.x, a.y), fmaxf(a.z, a.w)),
                   fmaxf(fmaxf(b.x, b.y), fmaxf(b.z, b.w)));
#pragma unroll
  for (int off = 32; off; off >>= 1) mx = fmaxf(mx, __shfl_xor(mx, off));
  __shared__ float red[4];
  const int wid = t >> 6, ln = t & 63;
  if (ln == 0) red[wid] = mx;
  __syncthreads();
  mx = fmaxf(fmaxf(red[0], red[1]), fmaxf(red[2], red[3]));

  a.x = __expf(a.x - mx); a.y = __expf(a.y - mx);
  a.z = __expf(a.z - mx); a.w = __expf(a.w - mx);
  b.x = __expf(b.x - mx); b.y = __expf(b.y - mx);
  b.z = __expf(b.z - mx); b.w = __expf(b.w - mx);

  float s = a.x + a.y + a.z + a.w + b.x + b.y + b.z + b.w;
#pragma unroll
  for (int off = 32; off; off >>= 1) s += __shfl_xor(s, off);
  __syncthreads();
  if (ln == 0) red[wid] = s;
  __syncthreads();
  s = red[0] + red[1] + red[2] + red[3];

  const float inv = 1.0f / s;
  a.x *= inv; a.y *= inv; a.z *= inv; a.w *= inv;
  b.x *= inv; b.y *= inv; b.z *= inv; b.w *= inv;
  *(float4*)(p + t * 4) = a;
  *(float4*)(p + 1024 + t * 4) = b;
}

extern "C" void kernel_launch(void* const* d_in, const int* in_sizes, int n_in,
                              void* d_out, int out_size, void* d_ws, size_t ws_size,
                              hipStream_t stream) {
  const float* x  = (const float*)d_in[0];
  const float* Wq = (const float*)d_in[1];
  const float* Wk = (const float*)d_in[2];
  const float* Wv = (const float*)d_in[3];
  float* out = (float*)d_out;

  // Qb/Kb scratch inside d_out's out0 region (dead after scores GEMM,
  // overwritten by final PV kernel). Vt is the only d_ws use (25.2 MB).
  u16* Qb = (u16*)d_out;                      // [16384][768] bf16
  u16* Kb = Qb + 16384ull * 768;              // [16384][768] bf16 (ends exactly at out0 end)
  u16* Vt = (u16*)d_ws;                       // [8][768][2048] bf16
  float* wts = out + 8ull * 2048 * 768;       // attention weights region of d_out

  const dim3 blk(256, 1, 1);
  const float isq = 1.0f / sqrtf(768.0f);

  // QKV projections: M=16384, N=768, K=768 (x fp32, W fp32 -> bf16 staging)
  gemm_nt<float, float, OUT_BF16><<<dim3(256, 12, 1), blk, 0, stream>>>(
      x, Wq, (void*)Qb, 768, 768, 768, 768, 0, 0, 0, 1.0f);
  gemm_nt<float, float, OUT_BF16><<<dim3(256, 12, 1), blk, 0, stream>>>(
      x, Wk, (void*)Kb, 768, 768, 768, 768, 0, 0, 0, 1.0f);
  gemm_nt<float, float, OUT_VT_BF16><<<dim3(256, 12, 1), blk, 0, stream>>>(
      x, Wv, (void*)Vt, 768, 768, 768, 0, 0, 0, 0, 1.0f);

  // scores: per batch M=N=2048, K=768; C = wts (fp32) * 1/sqrt(D)
  gemm_nt<u16, u16, OUT_F32><<<dim3(32, 32, 8), blk, 0, stream>>>(
      Qb, Kb, (void*)wts, 768, 768, 768, 2048,
      2048ll * 768, 2048ll * 768, 2048ll * 2048, isq);

  // softmax in place over 16384 rows
  softmax_rows<<<dim3(16384, 1, 1), blk, 0, stream>>>(wts);

  // PV: per batch M=2048, N=768, K=2048; A = attn fp32 (bf16 staged), Bt = Vt
  // (writes out0, overwriting the dead Qb/Kb scratch)
  gemm_nt<float, u16, OUT_F32><<<dim3(32, 12, 8), blk, 0, stream>>>(
      wts, Vt, (void*)out, 2048, 2048, 2048, 768,
      2048ll * 2048, 768ll * 2048, 2048ll * 768, 1.0f);
}

// Round 3
// 554.620 us; speedup vs baseline: 1.2138x; 1.2138x over previous
//
#include <hip/hip_runtime.h>
#include <cmath>

// ---------------------------------------------------------------------------
// SelfAttention: B=8, S=2048, D=768, fp32 in/out.
// R3: m97-style 128x128xBK64 MFMA GEMM with global_load_lds width=16.
//   pre-pass: x,Wq,Wk,Wv fp32 -> bf16 (stored in out1 region, dead later)
//   Q = xb Wqb^T ; K = xb Wkb^T ; V = xb Wvb^T   (all-bf16 GEMM)
//   Sc = Q K^T / sqrt(D) -> out1 ; softmax in place
//   wv = attn V  (A fp32 convert-staged, B=Vt via global_load_lds) -> out0
//
// Memory plan (ws kept at 25.2 MB — R2-proven safe):
//   d_out out0 [0,50.3MB):    Qb bf16 [16384][768], Kb bf16 [16384][768]
//                              (dead after scores; overwritten by PV)
//   d_out out1 [50.3,184.5MB): scratch before scores GEMM writes it:
//                              xb bf16 [16384][768], Wqb/Wkb/Wvb bf16 [768][768]
//   d_ws:                      Vt bf16 [8][768][2048]
// ---------------------------------------------------------------------------

typedef __bf16 v8bf __attribute__((ext_vector_type(8)));
typedef float  v4f  __attribute__((ext_vector_type(4)));
typedef unsigned short u16;

__device__ __forceinline__ u16 f2bf(float f) {
  union { float f; unsigned u; } v; v.f = f;
  unsigned r = v.u + 0x7fffu + ((v.u >> 16) & 1u);   // round-to-nearest-even
  return (u16)(r >> 16);
}

__device__ __forceinline__ uint4 pack8(const float* __restrict__ src) {
  float4 f0 = *(const float4*)src;
  float4 f1 = *(const float4*)(src + 4);
  union { uint4 u; u16 h[8]; } pk;
  pk.h[0] = f2bf(f0.x); pk.h[1] = f2bf(f0.y); pk.h[2] = f2bf(f0.z); pk.h[3] = f2bf(f0.w);
  pk.h[4] = f2bf(f1.x); pk.h[5] = f2bf(f1.y); pk.h[6] = f2bf(f1.z); pk.h[7] = f2bf(f1.w);
  return pk.u;
}

// async 16B global -> LDS (wave-uniform base + lane*16 layout)
__device__ __forceinline__ void gl_lds16(const void* g, void* l) {
  __builtin_amdgcn_global_load_lds(
      (const __attribute__((address_space(1))) unsigned*)g,
      (__attribute__((address_space(3))) unsigned*)l, 16, 0, 0);
}

enum { OUT_F32 = 0, OUT_BF16 = 1, OUT_VT_BF16 = 2 };

constexpr int BM = 128, BN = 128, BK = 64;

// C[M,N] = alpha * A[M,K] * B[N,K]^T  (NT). B always bf16. A bf16 or fp32.
// grid: (M/128, N/128, batch); 256 threads = 4 waves in 2x2, each 64x64 out.
template <bool A_F32, int MODE>
__global__ __launch_bounds__(256)
void gemm128(const void* __restrict__ Ag_, const void* __restrict__ Bg_,
             void* __restrict__ Cg, int K, int lda, int ldb, int ldc,
             long long sA, long long sB, long long sC, float alpha) {
  __shared__ u16 As[BM * BK];   // unpadded: global_load_lds layout constraint
  __shared__ u16 Bs[BN * BK];

  const int z  = blockIdx.z;
  const int m0 = blockIdx.x * BM;
  const int n0 = blockIdx.y * BN;

  const int t    = threadIdx.x;
  const int lane = t & 63;
  const int w    = t >> 6;
  const int wm   = (w & 1) * 64;     // wave's 64x64 quadrant
  const int wn   = (w >> 1) * 64;
  const int fr   = lane & 15;        // fragment row
  const int fk   = (lane >> 4) * 8;  // fragment k offset (quad*8)

  const u16* Bp = (const u16*)Bg_ + (size_t)z * (size_t)sB;

  v4f acc[4][4];
#pragma unroll
  for (int i = 0; i < 4; ++i)
#pragma unroll
    for (int j = 0; j < 4; ++j) acc[i][j] = (v4f){0.f, 0.f, 0.f, 0.f};

  for (int kt = 0; kt < K; kt += BK) {
    // --- stage B tile (bf16, async direct-to-LDS, 16B/lane) ---
#pragma unroll
    for (int j = 0; j < 4; ++j) {
      const int c   = (w * 4 + j) * 64 + lane;   // 16B chunk index, 0..1023
      const int row = c >> 3, kc = (c & 7) * 8;
      gl_lds16(Bp + (size_t)(n0 + row) * ldb + kt + kc, &Bs[c * 8]);
    }
    // --- stage A tile ---
    if constexpr (A_F32) {
      const float* Ap = (const float*)Ag_ + (size_t)z * (size_t)sA;
#pragma unroll
      for (int j = 0; j < 4; ++j) {
        const int e   = (j * 256 + t) * 8;       // element index in 128x64 tile
        const int row = e >> 6, kk = e & 63;
        uint4 pk = pack8(Ap + (size_t)(m0 + row) * lda + kt + kk);
        *(uint4*)&As[e] = pk;
      }
    } else {
      const u16* Ap = (const u16*)Ag_ + (size_t)z * (size_t)sA;
#pragma unroll
      for (int j = 0; j < 4; ++j) {
        const int c   = (w * 4 + j) * 64 + lane;
        const int row = c >> 3, kc = (c & 7) * 8;
        gl_lds16(Ap + (size_t)(m0 + row) * lda + kt + kc, &As[c * 8]);
      }
    }
    __syncthreads();   // drains vmcnt (global_load_lds) + lgkmcnt (ds_write)

    // --- 32 MFMAs per wave over BK=64 ---
#pragma unroll
    for (int kk = 0; kk < BK; kk += 32) {
      v8bf af[4], bv[4];
#pragma unroll
      for (int i = 0; i < 4; ++i) {
        af[i] = *(const v8bf*)&As[(wm + i * 16 + fr) * BK + kk + fk];
        bv[i] = *(const v8bf*)&Bs[(wn + i * 16 + fr) * BK + kk + fk];
      }
#pragma unroll
      for (int mi = 0; mi < 4; ++mi)
#pragma unroll
        for (int ni = 0; ni < 4; ++ni)
          acc[mi][ni] =
              __builtin_amdgcn_mfma_f32_16x16x32_bf16(af[mi], bv[ni], acc[mi][ni], 0, 0, 0);
    }
    __syncthreads();
  }

  // epilogue: C/D layout col=lane&15, row=(lane>>4)*4+reg
  const int r0 = (lane >> 4) * 4;
#pragma unroll
  for (int mi = 0; mi < 4; ++mi) {
#pragma unroll
    for (int ni = 0; ni < 4; ++ni) {
      v4f v = acc[mi][ni];
      const int grow0 = m0 + wm + mi * 16 + r0;
      const int gcol  = n0 + wn + ni * 16 + fr;
      if constexpr (MODE == OUT_F32) {
        float* C = (float*)Cg + (size_t)z * (size_t)sC;
#pragma unroll
        for (int r = 0; r < 4; ++r)
          C[(size_t)(grow0 + r) * ldc + gcol] = v[r] * alpha;
      } else if constexpr (MODE == OUT_BF16) {
        u16* C = (u16*)Cg;
#pragma unroll
        for (int r = 0; r < 4; ++r)
          C[(size_t)(grow0 + r) * ldc + gcol] = f2bf(v[r]);
      } else {  // OUT_VT_BF16: C[b][d][s], rows are 4 consecutive s
        u16* C = (u16*)Cg;
        size_t base = (size_t)(grow0 >> 11) * (768ull * 2048ull) +
                      (size_t)gcol * 2048ull + (size_t)(grow0 & 2047);
        ushort4 st;
        st.x = f2bf(v[0]); st.y = f2bf(v[1]); st.z = f2bf(v[2]); st.w = f2bf(v[3]);
        *(ushort4*)&C[base] = st;
      }
    }
  }
}

// fp32 -> bf16 copy, 8 elements/thread
__global__ __launch_bounds__(256)
void cvt_bf16(const float* __restrict__ src, u16* __restrict__ dst, int n8) {
  const int i = blockIdx.x * 256 + threadIdx.x;
  if (i < n8) *(uint4*)(dst + (size_t)i * 8) = pack8(src + (size_t)i * 8);
}

// three small weight matrices in one launch (blockIdx.y selects)
__global__ __launch_bounds__(256)
void cvt3_bf16(const float* __restrict__ s0, const float* __restrict__ s1,
               const float* __restrict__ s2, u16* __restrict__ d0,
               u16* __restrict__ d1, u16* __restrict__ d2, int n8) {
  const float* s = blockIdx.y == 0 ? s0 : blockIdx.y == 1 ? s1 : s2;
  u16*         d = blockIdx.y == 0 ? d0 : blockIdx.y == 1 ? d1 : d2;
  const int i = blockIdx.x * 256 + threadIdx.x;
  if (i < n8) *(uint4*)(d + (size_t)i * 8) = pack8(s + (size_t)i * 8);
}

// in-place softmax over rows of 2048 fp32; one block per row
__global__ __launch_bounds__(256) void softmax_rows(float* __restrict__ w) {
  float* p = w + (size_t)blockIdx.x * 2048;
  const int t = threadIdx.x;
  float4 a = *(float4*)(p + t * 4);
  float4 b = *(float4*)(p + 1024 + t * 4);

  float mx = fmaxf(fmaxf(fmaxf(a.x, a.y), fmaxf(a.z, a.w)),
                   fmaxf(fmaxf(b.x, b.y), fmaxf(b.z, b.w)));
#pragma unroll
  for (int off = 32; off; off >>= 1) mx = fmaxf(mx, __shfl_xor(mx, off));
  __shared__ float red[4];
  const int wid = t >> 6, ln = t & 63;
  if (ln == 0) red[wid] = mx;
  __syncthreads();
  mx = fmaxf(fmaxf(red[0], red[1]), fmaxf(red[2], red[3]));

  a.x = __expf(a.x - mx); a.y = __expf(a.y - mx);
  a.z = __expf(a.z - mx); a.w = __expf(a.w - mx);
  b.x = __expf(b.x - mx); b.y = __expf(b.y - mx);
  b.z = __expf(b.z - mx); b.w = __expf(b.w - mx);

  float s = a.x + a.y + a.z + a.w + b.x + b.y + b.z + b.w;
#pragma unroll
  for (int off = 32; off; off >>= 1) s += __shfl_xor(s, off);
  __syncthreads();
  if (ln == 0) red[wid] = s;
  __syncthreads();
  s = red[0] + red[1] + red[2] + red[3];

  const float inv = 1.0f / s;
  a.x *= inv; a.y *= inv; a.z *= inv; a.w *= inv;
  b.x *= inv; b.y *= inv; b.z *= inv; b.w *= inv;
  *(float4*)(p + t * 4) = a;
  *(float4*)(p + 1024 + t * 4) = b;
}

extern "C" void kernel_launch(void* const* d_in, const int* in_sizes, int n_in,
                              void* d_out, int out_size, void* d_ws, size_t ws_size,
                              hipStream_t stream) {
  const float* x  = (const float*)d_in[0];
  const float* Wq = (const float*)d_in[1];
  const float* Wk = (const float*)d_in[2];
  const float* Wv = (const float*)d_in[3];
  float* out = (float*)d_out;
  float* wts = out + 8ull * 2048 * 768;   // out1 region (attention weights)

  // bf16 scratch inside d_out (see header comment)
  u16* Qb  = (u16*)d_out;                 // out0: [16384][768]
  u16* Kb  = Qb + 16384ull * 768;         //       [16384][768]
  u16* xb  = (u16*)wts;                   // out1 scratch: [16384][768]
  u16* Wqb = xb + 16384ull * 768;         //               [768][768] x3
  u16* Wkb = Wqb + 768ull * 768;
  u16* Wvb = Wkb + 768ull * 768;
  u16* Vt  = (u16*)d_ws;                  // ws: [8][768][2048] (25.2 MB)

  const dim3 blk(256, 1, 1);
  const float isq = 1.0f / sqrtf(768.0f);

  // pre-convert inputs to bf16
  cvt_bf16<<<dim3(6144, 1, 1), blk, 0, stream>>>(x, xb, 16384 * 768 / 8);
  cvt3_bf16<<<dim3(288, 3, 1), blk, 0, stream>>>(Wq, Wk, Wv, Wqb, Wkb, Wvb,
                                                 768 * 768 / 8);

  // QKV projections: M=16384, N=768, K=768 (all bf16)
  gemm128<false, OUT_BF16><<<dim3(128, 6, 1), blk, 0, stream>>>(
      xb, Wqb, (void*)Qb, 768, 768, 768, 768, 0, 0, 0, 1.0f);
  gemm128<false, OUT_BF16><<<dim3(128, 6, 1), blk, 0, stream>>>(
      xb, Wkb, (void*)Kb, 768, 768, 768, 768, 0, 0, 0, 1.0f);
  gemm128<false, OUT_VT_BF16><<<dim3(128, 6, 1), blk, 0, stream>>>(
      xb, Wvb, (void*)Vt, 768, 768, 768, 0, 0, 0, 0, 1.0f);

  // scores: per batch M=N=2048, K=768 -> wts fp32 * 1/sqrt(D)
  gemm128<false, OUT_F32><<<dim3(16, 16, 8), blk, 0, stream>>>(
      Qb, Kb, (void*)wts, 768, 768, 768, 2048,
      2048ll * 768, 2048ll * 768, 2048ll * 2048, isq);

  // softmax in place over 16384 rows
  softmax_rows<<<dim3(16384, 1, 1), blk, 0, stream>>>(wts);

  // PV: per batch M=2048, N=768, K=2048; A=attn fp32 (convert-staged), B=Vt
  gemm128<true, OUT_F32><<<dim3(16, 6, 8), blk, 0, stream>>>(
      wts, Vt, (void*)out, 2048, 2048, 2048, 768,
      2048ll * 2048, 768ll * 2048, 2048ll * 768, 1.0f);
}

// Round 4
// 490.554 us; speedup vs baseline: 1.3724x; 1.1306x over previous
//
#include <hip/hip_runtime.h>
#include <cmath>

// ---------------------------------------------------------------------------
// SelfAttention: B=8, S=2048, D=768, fp32 in/out.
// R4: R3 + XOR chunk-swizzled LDS layout. R3's unpadded row stride (128 B =
// exactly 32 banks) made every fragment ds_read_b128 16-way bank-conflicted
// (SQ_LDS_BANK_CONFLICT 1.9e7/dispatch, MfmaUtil 16%). global_load_lds pins
// the LDS destination (base + lane*16) so we swizzle the SOURCE instead:
// LDS slot [row][cpos] holds global chunk (cpos ^ (row&7)). Fragment reads
// then spread across all 32 banks (2-way max = free).
//
// Memory plan (unchanged, R2-proven safe; ws use = 25.2 MB):
//   d_out out0 [0,50.3MB):    Qb bf16 [16384][768], Kb bf16 [16384][768]
//   d_out out1 [50.3,184.5MB): pre-scores scratch: xb bf16 [16384][768],
//                              Wqb/Wkb/Wvb bf16 [768][768]
//   d_ws:                      Vt bf16 [8][768][2048]
// ---------------------------------------------------------------------------

typedef __bf16 v8bf __attribute__((ext_vector_type(8)));
typedef float  v4f  __attribute__((ext_vector_type(4)));
typedef unsigned short u16;

__device__ __forceinline__ u16 f2bf(float f) {
  union { float f; unsigned u; } v; v.f = f;
  unsigned r = v.u + 0x7fffu + ((v.u >> 16) & 1u);   // round-to-nearest-even
  return (u16)(r >> 16);
}

__device__ __forceinline__ uint4 pack8(const float* __restrict__ src) {
  float4 f0 = *(const float4*)src;
  float4 f1 = *(const float4*)(src + 4);
  union { uint4 u; u16 h[8]; } pk;
  pk.h[0] = f2bf(f0.x); pk.h[1] = f2bf(f0.y); pk.h[2] = f2bf(f0.z); pk.h[3] = f2bf(f0.w);
  pk.h[4] = f2bf(f1.x); pk.h[5] = f2bf(f1.y); pk.h[6] = f2bf(f1.z); pk.h[7] = f2bf(f1.w);
  return pk.u;
}

// async 16B global -> LDS (wave-uniform base + lane*16 layout)
__device__ __forceinline__ void gl_lds16(const void* g, void* l) {
  __builtin_amdgcn_global_load_lds(
      (const __attribute__((address_space(1))) unsigned*)g,
      (__attribute__((address_space(3))) unsigned*)l, 16, 0, 0);
}

enum { OUT_F32 = 0, OUT_BF16 = 1, OUT_VT_BF16 = 2 };

constexpr int BM = 128, BN = 128, BK = 64;

// C[M,N] = alpha * A[M,K] * B[N,K]^T  (NT). B always bf16. A bf16 or fp32.
// grid: (M/128, N/128, batch); 256 threads = 4 waves in 2x2, each 64x64 out.
// LDS tile = [128 rows][8 chunks of 16B]; slot cpos holds global chunk
// cpos ^ (row & 7)  (XOR swizzle -> conflict-free fragment reads).
template <bool A_F32, int MODE>
__global__ __launch_bounds__(256)
void gemm128(const void* __restrict__ Ag_, const void* __restrict__ Bg_,
             void* __restrict__ Cg, int K, int lda, int ldb, int ldc,
             long long sA, long long sB, long long sC, float alpha) {
  __shared__ u16 As[BM * BK];
  __shared__ u16 Bs[BN * BK];

  const int z  = blockIdx.z;
  const int m0 = blockIdx.x * BM;
  const int n0 = blockIdx.y * BN;

  const int t    = threadIdx.x;
  const int lane = t & 63;
  const int w    = t >> 6;
  const int wm   = (w & 1) * 64;     // wave's 64x64 quadrant
  const int wn   = (w >> 1) * 64;
  const int fr   = lane & 15;        // fragment row
  const int quad = lane >> 4;        // fragment k chunk (16B) within 32-elem k

  const u16* Bp = (const u16*)Bg_ + (size_t)z * (size_t)sB;

  v4f acc[4][4];
#pragma unroll
  for (int i = 0; i < 4; ++i)
#pragma unroll
    for (int j = 0; j < 4; ++j) acc[i][j] = (v4f){0.f, 0.f, 0.f, 0.f};

  for (int kt = 0; kt < K; kt += BK) {
    // --- stage B tile: LDS slot s (=row*8+cpos) gets global chunk cpos^(row&7)
#pragma unroll
    for (int j = 0; j < 4; ++j) {
      const int s   = (w * 4 + j) * 64 + lane;        // LDS 16B-slot, 0..1023
      const int row = s >> 3;
      const int gc  = (s & 7) ^ (row & 7);            // source chunk (swizzled)
      gl_lds16(Bp + (size_t)(n0 + row) * ldb + kt + gc * 8, &Bs[s * 8]);
    }
    // --- stage A tile ---
    if constexpr (A_F32) {
      const float* Ap = (const float*)Ag_ + (size_t)z * (size_t)sA;
#pragma unroll
      for (int j = 0; j < 4; ++j) {
        const int g   = j * 256 + t;                  // source-linear chunk id
        const int row = g >> 3, gc = g & 7;
        const int s   = (g & ~7) | (gc ^ (row & 7));  // swizzled LDS slot
        uint4 pk = pack8(Ap + (size_t)(m0 + row) * lda + kt + gc * 8);
        *(uint4*)&As[s * 8] = pk;
      }
    } else {
      const u16* Ap = (const u16*)Ag_ + (size_t)z * (size_t)sA;
#pragma unroll
      for (int j = 0; j < 4; ++j) {
        const int s   = (w * 4 + j) * 64 + lane;
        const int row = s >> 3;
        const int gc  = (s & 7) ^ (row & 7);
        gl_lds16(Ap + (size_t)(m0 + row) * lda + kt + gc * 8, &As[s * 8]);
      }
    }
    __syncthreads();   // drains vmcnt (global_load_lds) + lgkmcnt (ds_write)

    // --- 32 MFMAs per wave over BK=64 ---
#pragma unroll
    for (int kk = 0; kk < BK; kk += 32) {
      const int kc = (kk >> 3) + quad;                // chunk 0..7
      v8bf af[4], bv[4];
#pragma unroll
      for (int i = 0; i < 4; ++i) {
        const int ra = wm + i * 16 + fr;              // (ra&7)==(fr&7)
        const int rb = wn + i * 16 + fr;
        af[i] = *(const v8bf*)&As[(ra * 8 + (kc ^ (fr & 7))) * 8];
        bv[i] = *(const v8bf*)&Bs[(rb * 8 + (kc ^ (fr & 7))) * 8];
      }
#pragma unroll
      for (int mi = 0; mi < 4; ++mi)
#pragma unroll
        for (int ni = 0; ni < 4; ++ni)
          acc[mi][ni] =
              __builtin_amdgcn_mfma_f32_16x16x32_bf16(af[mi], bv[ni], acc[mi][ni], 0, 0, 0);
    }
    __syncthreads();
  }

  // epilogue: C/D layout col=lane&15, row=(lane>>4)*4+reg
  const int r0 = (lane >> 4) * 4;
#pragma unroll
  for (int mi = 0; mi < 4; ++mi) {
#pragma unroll
    for (int ni = 0; ni < 4; ++ni) {
      v4f v = acc[mi][ni];
      const int grow0 = m0 + wm + mi * 16 + r0;
      const int gcol  = n0 + wn + ni * 16 + fr;
      if constexpr (MODE == OUT_F32) {
        float* C = (float*)Cg + (size_t)z * (size_t)sC;
#pragma unroll
        for (int r = 0; r < 4; ++r)
          C[(size_t)(grow0 + r) * ldc + gcol] = v[r] * alpha;
      } else if constexpr (MODE == OUT_BF16) {
        u16* C = (u16*)Cg;
#pragma unroll
        for (int r = 0; r < 4; ++r)
          C[(size_t)(grow0 + r) * ldc + gcol] = f2bf(v[r]);
      } else {  // OUT_VT_BF16: C[b][d][s], rows are 4 consecutive s
        u16* C = (u16*)Cg;
        size_t base = (size_t)(grow0 >> 11) * (768ull * 2048ull) +
                      (size_t)gcol * 2048ull + (size_t)(grow0 & 2047);
        ushort4 st;
        st.x = f2bf(v[0]); st.y = f2bf(v[1]); st.z = f2bf(v[2]); st.w = f2bf(v[3]);
        *(ushort4*)&C[base] = st;
      }
    }
  }
}

// fp32 -> bf16 copy, 8 elements/thread
__global__ __launch_bounds__(256)
void cvt_bf16(const float* __restrict__ src, u16* __restrict__ dst, int n8) {
  const int i = blockIdx.x * 256 + threadIdx.x;
  if (i < n8) *(uint4*)(dst + (size_t)i * 8) = pack8(src + (size_t)i * 8);
}

// three small weight matrices in one launch (blockIdx.y selects)
__global__ __launch_bounds__(256)
void cvt3_bf16(const float* __restrict__ s0, const float* __restrict__ s1,
               const float* __restrict__ s2, u16* __restrict__ d0,
               u16* __restrict__ d1, u16* __restrict__ d2, int n8) {
  const float* s = blockIdx.y == 0 ? s0 : blockIdx.y == 1 ? s1 : s2;
  u16*         d = blockIdx.y == 0 ? d0 : blockIdx.y == 1 ? d1 : d2;
  const int i = blockIdx.x * 256 + threadIdx.x;
  if (i < n8) *(uint4*)(d + (size_t)i * 8) = pack8(s + (size_t)i * 8);
}

// in-place softmax over rows of 2048 fp32; one block per row
__global__ __launch_bounds__(256) void softmax_rows(float* __restrict__ w) {
  float* p = w + (size_t)blockIdx.x * 2048;
  const int t = threadIdx.x;
  float4 a = *(float4*)(p + t * 4);
  float4 b = *(float4*)(p + 1024 + t * 4);

  float mx = fmaxf(fmaxf(fmaxf(a.x, a.y), fmaxf(a.z, a.w)),
                   fmaxf(fmaxf(b.x, b.y), fmaxf(b.z, b.w)));
#pragma unroll
  for (int off = 32; off; off >>= 1) mx = fmaxf(mx, __shfl_xor(mx, off));
  __shared__ float red[4];
  const int wid = t >> 6, ln = t & 63;
  if (ln == 0) red[wid] = mx;
  __syncthreads();
  mx = fmaxf(fmaxf(red[0], red[1]), fmaxf(red[2], red[3]));

  a.x = __expf(a.x - mx); a.y = __expf(a.y - mx);
  a.z = __expf(a.z - mx); a.w = __expf(a.w - mx);
  b.x = __expf(b.x - mx); b.y = __expf(b.y - mx);
  b.z = __expf(b.z - mx); b.w = __expf(b.w - mx);

  float s = a.x + a.y + a.z + a.w + b.x + b.y + b.z + b.w;
#pragma unroll
  for (int off = 32; off; off >>= 1) s += __shfl_xor(s, off);
  __syncthreads();
  if (ln == 0) red[wid] = s;
  __syncthreads();
  s = red[0] + red[1] + red[2] + red[3];

  const float inv = 1.0f / s;
  a.x *= inv; a.y *= inv; a.z *= inv; a.w *= inv;
  b.x *= inv; b.y *= inv; b.z *= inv; b.w *= inv;
  *(float4*)(p + t * 4) = a;
  *(float4*)(p + 1024 + t * 4) = b;
}

extern "C" void kernel_launch(void* const* d_in, const int* in_sizes, int n_in,
                              void* d_out, int out_size, void* d_ws, size_t ws_size,
                              hipStream_t stream) {
  const float* x  = (const float*)d_in[0];
  const float* Wq = (const float*)d_in[1];
  const float* Wk = (const float*)d_in[2];
  const float* Wv = (const float*)d_in[3];
  float* out = (float*)d_out;
  float* wts = out + 8ull * 2048 * 768;   // out1 region (attention weights)

  // bf16 scratch inside d_out (see header comment)
  u16* Qb  = (u16*)d_out;                 // out0: [16384][768]
  u16* Kb  = Qb + 16384ull * 768;         //       [16384][768]
  u16* xb  = (u16*)wts;                   // out1 scratch: [16384][768]
  u16* Wqb = xb + 16384ull * 768;         //               [768][768] x3
  u16* Wkb = Wqb + 768ull * 768;
  u16* Wvb = Wkb + 768ull * 768;
  u16* Vt  = (u16*)d_ws;                  // ws: [8][768][2048] (25.2 MB)

  const dim3 blk(256, 1, 1);
  const float isq = 1.0f / sqrtf(768.0f);

  // pre-convert inputs to bf16
  cvt_bf16<<<dim3(6144, 1, 1), blk, 0, stream>>>(x, xb, 16384 * 768 / 8);
  cvt3_bf16<<<dim3(288, 3, 1), blk, 0, stream>>>(Wq, Wk, Wv, Wqb, Wkb, Wvb,
                                                 768 * 768 / 8);

  // QKV projections: M=16384, N=768, K=768 (all bf16)
  gemm128<false, OUT_BF16><<<dim3(128, 6, 1), blk, 0, stream>>>(
      xb, Wqb, (void*)Qb, 768, 768, 768, 768, 0, 0, 0, 1.0f);
  gemm128<false, OUT_BF16><<<dim3(128, 6, 1), blk, 0, stream>>>(
      xb, Wkb, (void*)Kb, 768, 768, 768, 768, 0, 0, 0, 1.0f);
  gemm128<false, OUT_VT_BF16><<<dim3(128, 6, 1), blk, 0, stream>>>(
      xb, Wvb, (void*)Vt, 768, 768, 768, 0, 0, 0, 0, 1.0f);

  // scores: per batch M=N=2048, K=768 -> wts fp32 * 1/sqrt(D)
  gemm128<false, OUT_F32><<<dim3(16, 16, 8), blk, 0, stream>>>(
      Qb, Kb, (void*)wts, 768, 768, 768, 2048,
      2048ll * 768, 2048ll * 768, 2048ll * 2048, isq);

  // softmax in place over 16384 rows
  softmax_rows<<<dim3(16384, 1, 1), blk, 0, stream>>>(wts);

  // PV: per batch M=2048, N=768, K=2048; A=attn fp32 (convert-staged), B=Vt
  gemm128<true, OUT_F32><<<dim3(16, 6, 8), blk, 0, stream>>>(
      wts, Vt, (void*)out, 2048, 2048, 2048, 768,
      2048ll * 2048, 768ll * 2048, 2048ll * 768, 1.0f);
}